// Round 1
// 90.958 us; speedup vs baseline: 1.0032x; 1.0032x over previous
//
#include <hip/hip_runtime.h>

// out[b,e,j] = bias[j] + sum_k weight[k,j] * y[b, e+k-7, j]
// y[b,e',j]  = sum_{i<=j} x[b,e',i] * dv^(j-i),  dv = clip(decay[1], 0.9, 1.0)
//
// R10: pipelined 64-row strip per block (2 tiles of 32), async global->LDS.
// R9's phases were serialized (stage | scan | conv) with VGPR-roundtrip
// staging: HBM idle during compute, compute idle during loads. Changes:
//  * global_load_lds width=16 staging: no VGPR round trip, loads queue
//    back-to-back, one waitcnt drain per phase.
//  * strip of 64 outputs: tile1 halo = tile0 tail (already scanned in LDS),
//    x read once per strip; LDS rows are globally linear: window row for
//    output o is always rows o..o+7.
//  * tile1 stage issued BEFORE tile0 scan+conv; drained by counted
//    s_waitcnt vmcnt(8) (8 newest vmem ops = conv0's 8 stores). Raw
//    "lgkmcnt(0); s_barrier" between scan<->conv keeps prefetch in flight
//    (__syncthreads would drain vmcnt(0)).
// LDS: 71 rows x 516 floats = 146,544 B -> 1 block/CU, 512 thr (8 waves).

#define B_    8
#define E_    2048
#define DIM_  512
#define K_    8
#define TE    32
#define STRIP 64
#define HALO  (K_ - 1)
#define NRA   (TE + HALO)        // 39 rows: halo + tile0
#define NRB   TE                 // 32 rows: tile1
#define LSTR  516                // float stride; 2064 B (16B aligned, pad vs banks)
#define NF4A  (NRA * 128)        // 4992 float4 chunks
#define NF4B  (NRB * 128)        // 4096 -> exactly 8 per thread

typedef __attribute__((address_space(1))) const float gfloat_t;
typedef __attribute__((address_space(3))) float       sfloat_t;

__device__ __forceinline__ void gld16(float* lds, const float* g)
{
    __builtin_amdgcn_global_load_lds((gfloat_t*)g, (sfloat_t*)lds, 16, 0, 0);
}

// Transposed two-level decayed scan, in place in LDS (verified R9 math).
// lane = r16 + 16*seg: each lane owns a 128-feature segment of one row.
__device__ __forceinline__ void scan_rows(float* __restrict__ yls, int rowbase,
    int nrows, int t, float d1, float d2, float d3, float d4,
    float d128, float d256)
{
    const int lane = t & 63, wave = t >> 6;
    const int r16 = lane & 15, seg = lane >> 4;
    const int rw  = wave * 16 + r16;
    if (rw >= nrows) return;
    float* sp = &yls[(rowbase + rw) * LSTR + seg * 128];

    // pass 1: segment-end Horner  E = sum_m x[m] * dv^(127-m)
    float E = 0.f;
    #pragma unroll 8
    for (int q = 0; q < 32; ++q) {
        const float4 v = *(const float4*)(sp + 4 * q);
        const float p = fmaf(d3, v.x, fmaf(d2, v.y, fmaf(d1, v.z, v.w)));
        E = fmaf(d4, E, p);
    }
    // level 2: carry across the row's 4 segments (2 shuffle hops)
    float S = E;
    float u1 = __shfl_up(S, 16, 64); if (seg >= 1) S = fmaf(d128, u1, S);
    float u2 = __shfl_up(S, 32, 64); if (seg >= 2) S = fmaf(d256, u2, S);
    float C  = __shfl_up(S, 16, 64); if (seg == 0) C = 0.f;   // S_{s-1}
    // pass 2: carry-propagating scan, 1 chained FMA per 4 elements
    float prev = C;
    #pragma unroll 8
    for (int q = 0; q < 32; ++q) {
        const float4 v = *(const float4*)(sp + 4 * q);
        const float p01   = fmaf(d1, v.x, v.y);
        const float p012  = fmaf(d1, p01, v.z);
        const float p0123 = fmaf(d1, p012, v.w);
        float4 yv;
        yv.x = fmaf(d1, prev, v.x);
        yv.y = fmaf(d2, prev, p01);
        yv.z = fmaf(d3, prev, p012);
        yv.w = fmaf(d4, prev, p0123);
        prev = yv.w;
        *(float4*)(sp + 4 * q) = yv;
    }
}

// Rolling-window conv over 8 consecutive outputs; LDS row for output o is o+k.
__device__ __forceinline__ void conv8(const float* __restrict__ yls,
    float* __restrict__ out, int b, int e0, int o0, int jf,
    const float4 (&w)[K_], float4 bi)
{
    float4 win[K_];
    #pragma unroll
    for (int k = 0; k < 7; ++k)
        win[k] = *(const float4*)(&yls[(o0 + k) * LSTR + jf]);
    #pragma unroll
    for (int i = 0; i < 8; ++i) {
        const int o = o0 + i;
        win[7] = *(const float4*)(&yls[(o + 7) * LSTR + jf]);
        float4 acc = bi;
        #pragma unroll
        for (int k = 0; k < K_; ++k) {
            acc.x = fmaf(w[k].x, win[k].x, acc.x);
            acc.y = fmaf(w[k].y, win[k].y, acc.y);
            acc.z = fmaf(w[k].z, win[k].z, acc.z);
            acc.w = fmaf(w[k].w, win[k].w, acc.w);
        }
        *(float4*)(out + ((size_t)b * E_ + e0 + o) * DIM_ + jf) = acc;
        #pragma unroll
        for (int k = 0; k < 7; ++k) win[k] = win[k + 1];   // renamed, free
    }
}

__global__ __launch_bounds__(512) void krl_p(
    const float* __restrict__ x,
    const float* __restrict__ weight,
    const float* __restrict__ bias,
    const float* __restrict__ decay,
    float* __restrict__ out)
{
    __shared__ float yls[(NRA + NRB) * LSTR];   // 146,544 B -> 1 block/CU

    const int t  = threadIdx.x;
    const int b  = blockIdx.y;
    const int e0 = blockIdx.x * STRIP;          // E_ % STRIP == 0
    const int ebase = e0 - HALO;
    const float* xb = x + (size_t)b * E_ * DIM_;

    // Conv operands issued first: arrive under staging latency, drained at
    // the first barrier, then held in VGPRs (36 regs).
    const int j = t & 127, h = t >> 7;          // h in 0..3
    const int jf = j * 4;
    float4 w[K_];
    #pragma unroll
    for (int k = 0; k < K_; ++k) w[k] = *(const float4*)(weight + k * DIM_ + jf);
    const float4 bi = *(const float4*)(bias + jf);

    float dv = decay[1];
    dv = fminf(fmaxf(dv, 0.9f), 1.0f);
    const float d1 = dv, d2 = dv * dv, d3 = d2 * dv, d4 = d2 * d2;
    float d128 = d4;                            // dv^4 -> square 5x = dv^128
    d128 *= d128; d128 *= d128; d128 *= d128; d128 *= d128; d128 *= d128;
    const float d256 = d128 * d128;

    // ---- Phase 0: async-stage region A (global rows ebase..ebase+38) ----
    // Each 64-lane wave-iteration covers one contiguous 1 KiB half-row:
    // row uniform, LDS dest = uniform base + lane*16 (linear rule holds).
    for (int i = t; i < NF4A; i += 512) {
        const int r = i >> 7, f4 = i & 127;
        const int eg = ebase + r;
        float* lp = &yls[r * LSTR + f4 * 4];
        if (eg >= 0) gld16(lp, xb + (size_t)eg * DIM_ + f4 * 4);
        else         *(float4*)lp = make_float4(0.f, 0.f, 0.f, 0.f);
    }
    __syncthreads();                            // vmcnt(0): region A resident

    // ---- Phase 1a: issue region B stage (rows e0+32..e0+63, always valid);
    // stays in flight across scan0 + conv0 (8 gld16 per thread, exactly) ----
    for (int i = t; i < NF4B; i += 512) {
        const int r = i >> 7, f4 = i & 127;
        gld16(&yls[(NRA + r) * LSTR + f4 * 4],
              xb + (size_t)(e0 + TE + r) * DIM_ + f4 * 4);
    }

    // ---- Phase 1b: scan region A (39 rows; waves 0-2, others fall through)
    scan_rows(yls, 0, NRA, t, d1, d2, d3, d4, d128, d256);

    // y_A ready: drain LDS only, keep B prefetch in flight.
    asm volatile("s_waitcnt lgkmcnt(0)\n\ts_barrier" ::: "memory");

    // ---- Phase 2: conv tile0 (outputs o = 0..31; 8 stores/thread) ----
    conv8(yls, out, b, e0, h * 8, jf, w, bi);

    // Drain exactly the 8 region-B loads: the 8 newest vmem ops are conv0's
    // stores; in-order vmcnt retirement => <=8 outstanding means B landed.
    asm volatile("s_waitcnt vmcnt(8)\n\ts_barrier" ::: "memory");

    // ---- Phase 3: scan region B (32 rows; waves 0-1) ----
    scan_rows(yls, NRA, NRB, t, d1, d2, d3, d4, d128, d256);

    asm volatile("s_waitcnt lgkmcnt(0)\n\ts_barrier" ::: "memory");

    // ---- Phase 4: conv tile1 (outputs o = 32..63; stores drain at endpgm)
    conv8(yls, out, b, e0, 32 + h * 8, jf, w, bi);
}

extern "C" void kernel_launch(void* const* d_in, const int* in_sizes, int n_in,
                              void* d_out, int out_size, void* d_ws, size_t ws_size,
                              hipStream_t stream) {
    const float* x      = (const float*)d_in[0];
    const float* weight = (const float*)d_in[1];
    const float* bias   = (const float*)d_in[2];
    const float* decay  = (const float*)d_in[3];
    float* out = (float*)d_out;

    dim3 grid(E_ / STRIP, B_);   // 32 x 8 = 256 blocks = 1 block/CU
    dim3 block(512);
    krl_p<<<grid, block, 0, stream>>>(x, weight, bias, decay, out);
}

// Round 3
// 89.935 us; speedup vs baseline: 1.0146x; 1.0114x over previous
//
#include <hip/hip_runtime.h>

// out[b,e,j] = bias[j] + sum_k weight[k,j] * y[b, e+k-7, j]
// y[b,e',j]  = sum_{i<=j} x[b,e',i] * dv^(j-i),  dv = clip(decay[1], 0.9, 1.0)
//
// R12: occupancy discriminator, geometry fixed. R11 died on LSTR=444 < 512
// (rows overlapped). Valid way to raise occupancy: keep TE=32/LSTR=516
// (R9's verified layout) but 512-thread blocks at 2 blocks/CU ->
// 16 waves/CU = 4 waves/SIMD, 2x the R9/R10 invariant. LDS 2 x 80,496 =
// 160,992 B <= 163,840 (fits exactly 2 blocks). Staging = R10's verified
// global_load_lds width=16; sync = plain __syncthreads (counted-vmcnt
// pipelining measured null in R10). Null readout (90-92 us) => harness
// floor, declare roofline.

#define B_    8
#define E_    2048
#define DIM_  512
#define K_    8
#define TE    32
#define HALO  (K_ - 1)
#define NROWS (TE + HALO)      // 39 rows
#define LSTR  516              // floats; >=512, mult of 4; bank rotation 4 -> 2-way (free)
#define NF4   (NROWS * 128)    // 4992 float4 chunks

typedef __attribute__((address_space(1))) const float gfloat_t;
typedef __attribute__((address_space(3))) float       sfloat_t;

__device__ __forceinline__ void gld16(float* lds, const float* g)
{
    __builtin_amdgcn_global_load_lds((gfloat_t*)g, (sfloat_t*)lds, 16, 0, 0);
}

__global__ __launch_bounds__(512) void krl_w(
    const float* __restrict__ x,
    const float* __restrict__ weight,
    const float* __restrict__ bias,
    const float* __restrict__ decay,
    float* __restrict__ out)
{
    __shared__ float yls[NROWS * LSTR];   // 80,496 B -> 2 blocks/CU

    const int t  = threadIdx.x;
    const int b  = blockIdx.y;
    const int e0 = blockIdx.x * TE;       // E_ % TE == 0
    const int ebase = e0 - HALO;
    const float* xb = x + (size_t)b * E_ * DIM_;

    // Conv operands first: their loads arrive under staging latency.
    const int j = t & 127, h = t >> 7;    // h in 0..3
    const int jf = j * 4;
    float4 w[K_];
    #pragma unroll
    for (int k = 0; k < K_; ++k) w[k] = *(const float4*)(weight + k * DIM_ + jf);
    const float4 bi = *(const float4*)(bias + jf);

    float dv = decay[1];
    dv = fminf(fmaxf(dv, 0.9f), 1.0f);
    const float d1 = dv, d2 = dv * dv, d3 = d2 * dv, d4 = d2 * d2;
    float d128 = d4;                      // dv^4 -> square 5x = dv^128
    d128 *= d128; d128 *= d128; d128 *= d128; d128 *= d128; d128 *= d128;
    const float d256 = d128 * d128;

    // ---- Phase 0: async-stage 39 x-rows into LDS (width-16, no VGPR trip).
    // Each wave-iteration: r uniform, LDS dest = uniform base + lane*16. ----
    for (int i = t; i < NF4; i += 512) {
        const int r = i >> 7, f4 = i & 127;
        const int eg = ebase + r;
        float* lp = &yls[r * LSTR + f4 * 4];
        if (eg >= 0) gld16(lp, xb + (size_t)eg * DIM_ + f4 * 4);
        else         *(float4*)lp = make_float4(0.f, 0.f, 0.f, 0.f);
    }
    __syncthreads();                      // drains vmcnt + lgkmcnt

    // ---- Phase 1: transposed two-level decayed scan (verified R9 math) ----
    {
        const int lane = t & 63, wave = t >> 6;
        const int r16 = lane & 15, seg = lane >> 4;
        const int row = wave * 16 + r16;  // waves 0-1 full, wave 2: 7 rows, 3-7 idle
        if (row < NROWS) {
            float* sp = &yls[row * LSTR + seg * 128];

            // pass 1: segment-end Horner  E = sum_m x[m] * dv^(127-m)
            float E = 0.f;
            #pragma unroll 8
            for (int q = 0; q < 32; ++q) {
                const float4 v = *(const float4*)(sp + 4 * q);
                const float p = fmaf(d3, v.x, fmaf(d2, v.y, fmaf(d1, v.z, v.w)));
                E = fmaf(d4, E, p);
            }
            // level 2: carry across the row's 4 segments (2 shuffle hops)
            float S = E;
            float u1 = __shfl_up(S, 16, 64); if (seg >= 1) S = fmaf(d128, u1, S);
            float u2 = __shfl_up(S, 32, 64); if (seg >= 2) S = fmaf(d256, u2, S);
            float C  = __shfl_up(S, 16, 64); if (seg == 0) C = 0.f;  // S_{s-1}
            // pass 2: carry-propagating scan
            float prev = C;
            #pragma unroll 8
            for (int q = 0; q < 32; ++q) {
                const float4 v = *(const float4*)(sp + 4 * q);
                const float p01   = fmaf(d1, v.x, v.y);
                const float p012  = fmaf(d1, p01, v.z);
                const float p0123 = fmaf(d1, p012, v.w);
                float4 yv;
                yv.x = fmaf(d1, prev, v.x);
                yv.y = fmaf(d2, prev, p01);
                yv.z = fmaf(d3, prev, p012);
                yv.w = fmaf(d4, prev, p0123);
                prev = yv.w;
                *(float4*)(sp + 4 * q) = yv;
            }
        }
    }
    __syncthreads();

    // ---- Phase 2: rolling-window conv; 8 outputs per thread ----
    {
        const int o0 = h * 8;             // h in 0..3 -> outputs 0..31
        float4 win[K_];
        #pragma unroll
        for (int k = 0; k < 7; ++k)
            win[k] = *(const float4*)(&yls[(o0 + k) * LSTR + jf]);
        #pragma unroll
        for (int i = 0; i < 8; ++i) {
            const int o = o0 + i;
            win[7] = *(const float4*)(&yls[(o + 7) * LSTR + jf]);
            float4 acc = bi;
            #pragma unroll
            for (int k = 0; k < K_; ++k) {
                acc.x = fmaf(w[k].x, win[k].x, acc.x);
                acc.y = fmaf(w[k].y, win[k].y, acc.y);
                acc.z = fmaf(w[k].z, win[k].z, acc.z);
                acc.w = fmaf(w[k].w, win[k].w, acc.w);
            }
            *(float4*)(out + ((size_t)b * E_ + e0 + o) * DIM_ + jf) = acc;
            #pragma unroll
            for (int k = 0; k < 7; ++k) win[k] = win[k + 1];  // renamed, free
        }
    }
}

extern "C" void kernel_launch(void* const* d_in, const int* in_sizes, int n_in,
                              void* d_out, int out_size, void* d_ws, size_t ws_size,
                              hipStream_t stream) {
    const float* x      = (const float*)d_in[0];
    const float* weight = (const float*)d_in[1];
    const float* bias   = (const float*)d_in[2];
    const float* decay  = (const float*)d_in[3];
    float* out = (float*)d_out;

    dim3 grid(E_ / TE, B_);    // 64 x 8 = 512 blocks = 2 blocks/CU
    dim3 block(512);
    krl_w<<<grid, block, 0, stream>>>(x, weight, bias, decay, out);
}